// Round 9
// baseline (144.817 us; speedup 1.0000x reference)
//
#include <hip/hip_runtime.h>

#define PEPS  1e-5f
#define LOG2E 1.4426950408889634f

__device__ __forceinline__ float fast_rcp(float x) { return __builtin_amdgcn_rcpf(x); }

// out = x * (0.5 + 0.5 * sigmoid((x-m)*rs)), nrs2 = -rs*log2e, mrs = m*rs*log2e
__device__ __forceinline__ float patch_one(float x, float nrs2, float mrs) {
    const float e = __builtin_amdgcn_exp2f(fmaf(x, nrs2, mrs));
    return x * fmaf(0.5f, fast_rcp(1.0f + e), 0.5f);
}

__device__ __forceinline__ void wave_reduce2(float& a, float& b) {
#pragma unroll
    for (int off = 32; off; off >>= 1) {
        a += __shfl_xor(a, off);
        b += __shfl_xor(b, off);
    }
}

// async global->LDS, 16 B/lane: LDS dest = wave-uniform base + lane*16 (HW),
// global src per-lane.
__device__ __forceinline__ void gld_lds16(const float* g, float* l) {
    __builtin_amdgcn_global_load_lds(
        (const __attribute__((address_space(1))) void*)g,
        (__attribute__((address_space(3))) void*)l, 16, 0, 0);
}

// Persistent pipeline, grid=256 x 1024 thr (1 block/CU, 16 waves), 4 images each.
// Tile (128 KiB LDS) holds the TOP 32 rows of each 64-row patch band of the
// current image (prefetched during the previous image's compute/store); every
// wave reads its patch's top half from LDS, bottom half from global (balanced,
// r8 had an 8v8 wave split that stalled at the D barrier).
// Raw s_barrier + counted s_waitcnt replaces __syncthreads at A/D/G: r8's
// __syncthreads emitted vmcnt(0) before each s_barrier, force-draining the
// prefetch at G and the stores at A (the ~25us gap to the BW floor).
__global__ __launch_bounds__(1024) void fused_pyramid_pipe2(
    const float* __restrict__ in, float* __restrict__ out)
{
    constexpr int W   = 256;
    constexpr int IMG = W * W;
    __shared__ float tile[32768];               // 128 rows x 256 cols
    __shared__ float redS[16], redQ[16];        // pass-2 partials
    __shared__ float redS2[16], redQ2[16];      // pass-3 partials

    const int tid   = threadIdx.x;
    const int wave  = tid >> 6;                 // 0..15 -> 4x4 grid of 64x64 patches
    const int lane  = tid & 63;
    const int pr    = wave >> 2;
    const int pc    = wave & 3;
    const int rlane = lane >> 4;                // 0..3
    const int c4    = lane & 15;
    const int bid   = blockIdx.x;

    // tile row t <-> image row (t>>5)*64 + (t&31)  (top 32 rows of each band)
    auto prefetch_img = [&](const float* src) {
#pragma unroll
        for (int i = 0; i < 8; ++i) {
            const int c  = wave * 8 + i;                    // 0..127 tile rows
            const int gr = ((c >> 5) << 6) + (c & 31);      // image row
            gld_lds16(src + gr * W + lane * 4, &tile[c * W]);
        }
    };

    // ---- prologue: prefetch image bid's band-tops ---------------------------
    prefetch_img(in + (size_t)bid * IMG);

    for (int k = 0; k < 4; ++k) {
        const int img = bid + k * 256;
        const float* in_img  = in  + (size_t)img * IMG;
        float*       out_img = out + (size_t)img * IMG;

        // A: wait own prefetch (counted: leave stores in flight), then barrier
        if (k == 0) { asm volatile("s_waitcnt vmcnt(0)" ::: "memory"); }
        else        { asm volatile("s_waitcnt vmcnt(16)" ::: "memory"); }
        __builtin_amdgcn_s_barrier();
        __builtin_amdgcn_sched_barrier(0);

        // B: bottom half (rows 32..63 of patch) from global — issue first
        float4 v[16];
        const float* gl = in_img + (size_t)(pr * 64 + 32) * W + pc * 64;
#pragma unroll
        for (int u = 0; u < 8; ++u) {
            const int r = u * 4 + rlane;
            v[8 + u] = *reinterpret_cast<const float4*>(gl + (size_t)r * W + c4 * 4);
        }
        //    top half (rows 0..31) from LDS, accumulate pass-1 sums meanwhile
        const float* tl = &tile[(pr * 32) * W + pc * 64];
        float s = 0.f, q = 0.f;
#pragma unroll
        for (int u = 0; u < 8; ++u) {
            const int r = u * 4 + rlane;
            const float4 t = *reinterpret_cast<const float4*>(tl + r * W + c4 * 4);
            v[u] = t;
            s += (t.x + t.y) + (t.z + t.w);
            q = fmaf(t.x, t.x, fmaf(t.y, t.y, fmaf(t.z, t.z, fmaf(t.w, t.w, q))));
        }
#pragma unroll
        for (int u = 8; u < 16; ++u) {
            const float4 t = v[u];
            s += (t.x + t.y) + (t.z + t.w);
            q = fmaf(t.x, t.x, fmaf(t.y, t.y, fmaf(t.z, t.z, fmaf(t.w, t.w, q))));
        }

        // C: pass 1 (s=64), wave-local
        wave_reduce2(s, q);
        float m  = s * (1.0f / 4096.0f);
        float rs = rsqrtf(fmaf(-m, m, q * (1.0f / 4096.0f)) + PEPS);
        float nrs2 = rs * -LOG2E;
        float mrs  = m * rs * LOG2E;

        float s2 = 0.f, q2 = 0.f;
#pragma unroll
        for (int u = 0; u < 16; ++u) {
            float4 t = v[u];
            t.x = patch_one(t.x, nrs2, mrs);
            t.y = patch_one(t.y, nrs2, mrs);
            t.z = patch_one(t.z, nrs2, mrs);
            t.w = patch_one(t.w, nrs2, mrs);
            v[u] = t;
            s2 += (t.x + t.y) + (t.z + t.w);
            q2 = fmaf(t.x, t.x, fmaf(t.y, t.y, fmaf(t.z, t.z, fmaf(t.w, t.w, q2))));
        }

        // D: publish pass-2 partials; raw barrier (no vmcnt drain)
        wave_reduce2(s2, q2);
        if (lane == 0) { redS[wave] = s2; redQ[wave] = q2; }
        asm volatile("s_waitcnt lgkmcnt(0)" ::: "memory");
        __builtin_amdgcn_s_barrier();
        __builtin_amdgcn_sched_barrier(0);

        // E: issue next image's prefetch — flies under F/G/H and the counted A-wait
        if (k < 3) prefetch_img(in + (size_t)(bid + (k + 1) * 256) * IMG);
        __builtin_amdgcn_sched_barrier(0);

        // F: pass 2 (s=128): 2x2 wave group
        const int w00 = wave & ~5;
        {
            const float S = (redS[w00] + redS[w00 + 1]) + (redS[w00 + 4] + redS[w00 + 5]);
            const float Q = (redQ[w00] + redQ[w00 + 1]) + (redQ[w00 + 4] + redQ[w00 + 5]);
            m  = S * (1.0f / 16384.0f);
            rs = rsqrtf(fmaf(-m, m, Q * (1.0f / 16384.0f)) + PEPS);
        }
        nrs2 = rs * -LOG2E;
        mrs  = m * rs * LOG2E;

        float s3 = 0.f, q3 = 0.f;
#pragma unroll
        for (int u = 0; u < 16; ++u) {
            float4 t = v[u];
            t.x = patch_one(t.x, nrs2, mrs);
            t.y = patch_one(t.y, nrs2, mrs);
            t.z = patch_one(t.z, nrs2, mrs);
            t.w = patch_one(t.w, nrs2, mrs);
            v[u] = t;
            s3 += (t.x + t.y) + (t.z + t.w);
            q3 = fmaf(t.x, t.x, fmaf(t.y, t.y, fmaf(t.z, t.z, fmaf(t.w, t.w, q3))));
        }

        // G: pass 3 (s=256): publish; raw barrier (prefetch stays in flight!)
        wave_reduce2(s3, q3);
        if (lane == 0) { redS2[wave] = s3; redQ2[wave] = q3; }
        asm volatile("s_waitcnt lgkmcnt(0)" ::: "memory");
        __builtin_amdgcn_s_barrier();
        __builtin_amdgcn_sched_barrier(0);
        {
            float S = 0.f, Q = 0.f;
#pragma unroll
            for (int w = 0; w < 16; ++w) { S += redS2[w]; Q += redQ2[w]; }
            m  = S * (1.0f / 65536.0f);
            rs = rsqrtf(fmaf(-m, m, Q * (1.0f / 65536.0f)) + PEPS);
        }
        nrs2 = rs * -LOG2E;
        mrs  = m * rs * LOG2E;

        // H: apply pass 3 + store (top rows 0..31, bottom rows 32..63)
        {
            float* go = out_img + (size_t)(pr * 64) * W + pc * 64;
#pragma unroll
            for (int u = 0; u < 16; ++u) {
                const int r = ((u >> 3) << 5) + ((u & 7) << 2) + rlane;
                float4 t = v[u];
                t.x = patch_one(t.x, nrs2, mrs);
                t.y = patch_one(t.y, nrs2, mrs);
                t.z = patch_one(t.z, nrs2, mrs);
                t.w = patch_one(t.w, nrs2, mrs);
                *reinterpret_cast<float4*>(go + (size_t)r * W + c4 * 4) = t;
            }
        }
    }
}

extern "C" void kernel_launch(void* const* d_in, const int* in_sizes, int n_in,
                              void* d_out, int out_size, void* d_ws, size_t ws_size,
                              hipStream_t stream)
{
    const float* x = (const float*)d_in[0];
    float* out = (float*)d_out;
    // 1024 images, 256 persistent blocks x 4 images each; no workspace needed.
    fused_pyramid_pipe2<<<256, 1024, 0, stream>>>(x, out);
}

// Round 10
// 113.038 us; speedup vs baseline: 1.2811x; 1.2811x over previous
//
#include <hip/hip_runtime.h>

#define PEPS  1e-5f
#define LOG2E 1.4426950408889634f

__device__ __forceinline__ float fast_rcp(float x) { return __builtin_amdgcn_rcpf(x); }

// out = x * (0.5 + 0.5 * sigmoid((x-m)*rs)), with nrs2 = -rs*log2e, mrs = m*rs*log2e
__device__ __forceinline__ float patch_one(float x, float nrs2, float mrs) {
    const float e = __builtin_amdgcn_exp2f(fmaf(x, nrs2, mrs));
    return x * fmaf(0.5f, fast_rcp(1.0f + e), 0.5f);
}

__device__ __forceinline__ void wave_reduce2(float& a, float& b) {
#pragma unroll
    for (int off = 32; off; off >>= 1) {
        a += __shfl_xor(a, off);
        b += __shfl_xor(b, off);
    }
}

// async global->LDS, 16 B per lane. LDS dest is wave-uniform base (+lane*16 by HW),
// global src is per-lane.
__device__ __forceinline__ void gld_lds16(const float* g, float* l) {
    __builtin_amdgcn_global_load_lds(
        (const __attribute__((address_space(1))) void*)g,
        (__attribute__((address_space(3))) void*)l, 16, 0, 0);
}

// EXACT r8 structure (113.7us) with ONE change: the G barrier is a raw
// s_barrier + lgkmcnt(0) instead of __syncthreads. r8's __syncthreads at G
// emitted s_waitcnt vmcnt(0) before s_barrier, force-draining the E-prefetch
// after only phase F (~2us of overlap); the raw barrier keeps the 128 KiB
// prefetch in flight across G and H (~5-7us window). A and D stay
// __syncthreads (at D nothing is in flight; at A the implicit vmcnt(0) IS the
// wait the tile needs). r9 bundled three more edits and re-triggered the
// v[16] spill (VGPR=64/SGPR=112, WRITE +16MB scratch) -> reverted.
__global__ __launch_bounds__(1024) void fused_pyramid_pipe3(
    const float* __restrict__ in, float* __restrict__ out)
{
    constexpr int W   = 256;
    constexpr int IMG = W * W;                  // 65536 floats
    __shared__ float tile[32768];               // 128 KiB: rows 0..127 of current image
    __shared__ float redS[16], redQ[16];        // pass-2 partials
    __shared__ float redS2[16], redQ2[16];      // pass-3 partials

    const int tid   = threadIdx.x;
    const int wave  = tid >> 6;                 // 0..15 -> 4x4 grid of 64x64 patches
    const int lane  = tid & 63;
    const int pr    = wave >> 2;
    const int pc    = wave & 3;
    const int rlane = lane >> 4;                // row contribution from lane
    const int c4    = lane & 15;
    const int bid   = blockIdx.x;

    // ---- prologue: prefetch image bid's top half into LDS ------------------
    {
        const float* src = in + (size_t)bid * IMG;
#pragma unroll
        for (int i = 0; i < 8; ++i) {
            const int chunk = wave * 8 + i;     // 128 chunks x 1024 B cover 128 KiB
            gld_lds16(src + chunk * 256 + lane * 4, &tile[chunk * 256]);
        }
    }

    for (int k = 0; k < 4; ++k) {
        const int img = bid + k * 256;
        const float* in_img  = in  + (size_t)img * IMG;
        float*       out_img = out + (size_t)img * IMG;

        // A: wait prefetched tile (and prior stores), sync all waves
        __syncthreads();

        // B: load v[16] + pass-1 sums. Top waves from LDS, bottom from global.
        float4 v[16];
        float s = 0.f, q = 0.f;
        if (wave < 8) {
            const float* tl = &tile[(pr * 64) * W + pc * 64];
#pragma unroll
            for (int u = 0; u < 16; ++u) {
                const int r = u * 4 + rlane;
                const float4 t = *reinterpret_cast<const float4*>(tl + r * W + c4 * 4);
                v[u] = t;
                s += (t.x + t.y) + (t.z + t.w);
                q = fmaf(t.x, t.x, fmaf(t.y, t.y, fmaf(t.z, t.z, fmaf(t.w, t.w, q))));
            }
        } else {
            const float* gl = in_img + (size_t)(pr * 64) * W + pc * 64;
#pragma unroll
            for (int u = 0; u < 16; ++u) {
                const int r = u * 4 + rlane;
                const float4 t = *reinterpret_cast<const float4*>(gl + (size_t)r * W + c4 * 4);
                v[u] = t;
                s += (t.x + t.y) + (t.z + t.w);
                q = fmaf(t.x, t.x, fmaf(t.y, t.y, fmaf(t.z, t.z, fmaf(t.w, t.w, q))));
            }
        }

        // C: pass 1 (s=64), wave-local
        wave_reduce2(s, q);
        float m  = s * (1.0f / 4096.0f);
        float rs = rsqrtf(fmaf(-m, m, q * (1.0f / 4096.0f)) + PEPS);
        float nrs2 = rs * -LOG2E;
        float mrs  = m * rs * LOG2E;

        float s2 = 0.f, q2 = 0.f;
#pragma unroll
        for (int u = 0; u < 16; ++u) {
            float4 t = v[u];
            t.x = patch_one(t.x, nrs2, mrs);
            t.y = patch_one(t.y, nrs2, mrs);
            t.z = patch_one(t.z, nrs2, mrs);
            t.w = patch_one(t.w, nrs2, mrs);
            v[u] = t;
            s2 += (t.x + t.y) + (t.z + t.w);
            q2 = fmaf(t.x, t.x, fmaf(t.y, t.y, fmaf(t.z, t.z, fmaf(t.w, t.w, q2))));
        }

        // D: publish pass-2 partials (also fences all tile reads from B)
        wave_reduce2(s2, q2);
        if (lane == 0) { redS[wave] = s2; redQ[wave] = q2; }
        __syncthreads();

        // E: kick off next image's top-half prefetch (flies under F/G/H)
        if (k < 3) {
            const float* src = in + (size_t)(bid + (k + 1) * 256) * IMG;
#pragma unroll
            for (int i = 0; i < 8; ++i) {
                const int chunk = wave * 8 + i;
                gld_lds16(src + chunk * 256 + lane * 4, &tile[chunk * 256]);
            }
        }

        // F: pass 2 (s=128): 2x2 wave group
        const int w00 = wave & ~5;
        {
            const float S = (redS[w00] + redS[w00 + 1]) + (redS[w00 + 4] + redS[w00 + 5]);
            const float Q = (redQ[w00] + redQ[w00 + 1]) + (redQ[w00 + 4] + redQ[w00 + 5]);
            m  = S * (1.0f / 16384.0f);
            rs = rsqrtf(fmaf(-m, m, Q * (1.0f / 16384.0f)) + PEPS);
        }
        nrs2 = rs * -LOG2E;
        mrs  = m * rs * LOG2E;

        float s3 = 0.f, q3 = 0.f;
#pragma unroll
        for (int u = 0; u < 16; ++u) {
            float4 t = v[u];
            t.x = patch_one(t.x, nrs2, mrs);
            t.y = patch_one(t.y, nrs2, mrs);
            t.z = patch_one(t.z, nrs2, mrs);
            t.w = patch_one(t.w, nrs2, mrs);
            v[u] = t;
            s3 += (t.x + t.y) + (t.z + t.w);
            q3 = fmaf(t.x, t.x, fmaf(t.y, t.y, fmaf(t.z, t.z, fmaf(t.w, t.w, q3))));
        }

        // G: pass 3 (s=256): publish partials; raw barrier WITHOUT vmcnt drain
        //    (the one change vs r8 — prefetch stays in flight across G/H)
        wave_reduce2(s3, q3);
        if (lane == 0) { redS2[wave] = s3; redQ2[wave] = q3; }
        asm volatile("s_waitcnt lgkmcnt(0)" ::: "memory");
        __builtin_amdgcn_s_barrier();
        __builtin_amdgcn_sched_barrier(0);
        {
            float S = 0.f, Q = 0.f;
#pragma unroll
            for (int w = 0; w < 16; ++w) { S += redS2[w]; Q += redQ2[w]; }
            m  = S * (1.0f / 65536.0f);
            rs = rsqrtf(fmaf(-m, m, Q * (1.0f / 65536.0f)) + PEPS);
        }
        nrs2 = rs * -LOG2E;
        mrs  = m * rs * LOG2E;

        // H: apply pass 3 + store
        {
            float* go = out_img + (size_t)(pr * 64) * W + pc * 64;
#pragma unroll
            for (int u = 0; u < 16; ++u) {
                const int r = u * 4 + rlane;
                float4 t = v[u];
                t.x = patch_one(t.x, nrs2, mrs);
                t.y = patch_one(t.y, nrs2, mrs);
                t.z = patch_one(t.z, nrs2, mrs);
                t.w = patch_one(t.w, nrs2, mrs);
                *reinterpret_cast<float4*>(go + (size_t)r * W + c4 * 4) = t;
            }
        }
    }
}

extern "C" void kernel_launch(void* const* d_in, const int* in_sizes, int n_in,
                              void* d_out, int out_size, void* d_ws, size_t ws_size,
                              hipStream_t stream)
{
    const float* x = (const float*)d_in[0];
    float* out = (float*)d_out;
    // 1024 images, 256 persistent blocks x 4 images each; no workspace needed.
    fused_pyramid_pipe3<<<256, 1024, 0, stream>>>(x, out);
}